// Round 2
// baseline (223.271 us; speedup 1.0000x reference)
//
#include <hip/hip_runtime.h>

#define N_NODES 512
#define INNER   256
#define IN_DIM  128
#define EDGE_DIM 64
#define NH 8
#define HD 32

// ---------------------------------------------------------------------------
// Kernel 1: q/k/v projections  (512x128) @ (128x256) + bias, 3x
// One block computes 4 output rows; thread n owns output column n.
// ---------------------------------------------------------------------------
__global__ __launch_bounds__(256) void proj_qkv(
    const float* __restrict__ nodes,
    const float* __restrict__ Wq, const float* __restrict__ bq,
    const float* __restrict__ Wk, const float* __restrict__ bk,
    const float* __restrict__ Wv, const float* __restrict__ bv,
    float* __restrict__ q, float* __restrict__ k, float* __restrict__ v) {
  const int i0 = blockIdx.x * 4;
  const int n  = threadIdx.x;
  float aq[4] = {0.f, 0.f, 0.f, 0.f};
  float ak[4] = {0.f, 0.f, 0.f, 0.f};
  float av[4] = {0.f, 0.f, 0.f, 0.f};
  for (int c = 0; c < IN_DIM; ++c) {
    const float wq = Wq[c * INNER + n];
    const float wk = Wk[c * INNER + n];
    const float wv = Wv[c * INNER + n];
#pragma unroll
    for (int r = 0; r < 4; ++r) {
      const float x = nodes[(i0 + r) * IN_DIM + c];
      aq[r] = fmaf(x, wq, aq[r]);
      ak[r] = fmaf(x, wk, ak[r]);
      av[r] = fmaf(x, wv, av[r]);
    }
  }
  const float bqv = bq[n], bkv = bk[n], bvv = bv[n];
#pragma unroll
  for (int r = 0; r < 4; ++r) {
    q[(size_t)(i0 + r) * INNER + n] = aq[r] + bqv;
    k[(size_t)(i0 + r) * INNER + n] = ak[r] + bkv;
    v[(size_t)(i0 + r) * INNER + n] = av[r] + bvv;
  }
}

// ---------------------------------------------------------------------------
// Kernel 2: fused attention, one block per query row i, all 8 heads.
// Never materializes e = edges@We:
//   sim[h,j] = q_i.k_j + edges[i,j,:].qe[h] + qb[h]
//   out[n]   = sum_j attn v[j,n] + ae[h,:]@We[:,n] + asum[h]*be[n]
// ---------------------------------------------------------------------------
__global__ __launch_bounds__(256) void fused_graph_attn(
    const float* __restrict__ edges, const int* __restrict__ adjacency,
    const float* __restrict__ q, const float* __restrict__ k,
    const float* __restrict__ v,
    const float* __restrict__ We, const float* __restrict__ be,
    float* __restrict__ out) {
  const int i    = blockIdx.x;
  const int tid  = threadIdx.x;
  const int wid  = tid >> 6;
  const int lane = tid & 63;

  __shared__ float s_q[INNER];
  __shared__ float s_qe[NH * EDGE_DIM];
  __shared__ float s_qb[NH];
  __shared__ float s_adj[N_NODES];
  __shared__ float s_attn[NH][N_NODES];
  __shared__ float s_ae[NH * EDGE_DIM];
  __shared__ float s_red[32];
  __shared__ float s_mean;
  __shared__ float s_rdenom[NH];
  __shared__ float s_asum[NH];

  // ---- stage q row + adjacency row ----
  s_q[tid]        = q[(size_t)i * INNER + tid];
  s_adj[tid]       = (float)adjacency[(size_t)i * N_NODES + tid];
  s_adj[tid + 256] = (float)adjacency[(size_t)i * N_NODES + tid + 256];
  __syncthreads();

  // ---- qe[h][c] = sum_d q[h*32+d] * We[c, h*32+d];  qb[h] = q_h . be_h ----
#pragma unroll
  for (int pp = 0; pp < 2; ++pp) {
    const int idx = tid + pp * 256;
    const int h = idx >> 6, c = idx & 63;
    const float* wrow = We + (size_t)c * INNER + h * HD;
    const float* qh   = &s_q[h * HD];
    float acc = 0.f;
#pragma unroll
    for (int dd = 0; dd < 8; ++dd) {
      const float4 w4 = *(const float4*)(wrow + dd * 4);
      const float4 q4 = *(const float4*)(qh + dd * 4);
      acc += q4.x * w4.x + q4.y * w4.y + q4.z * w4.z + q4.w * w4.w;
    }
    s_qe[idx] = acc;
  }
  if (tid < NH) {
    float acc = 0.f;
    for (int d = 0; d < HD; ++d) acc += s_q[tid * HD + d] * be[tid * HD + d];
    s_qb[tid] = acc;
  }
  __syncthreads();

  // ---- pass 1: sim[h][j] for all 8 heads ----
  const float scale = 0.17677669529663687f;  // 1/sqrt(32)
  for (int p = 0; p < 2; ++p) {
    const int j = tid + p * 256;
    float acc[NH];
#pragma unroll
    for (int h = 0; h < NH; ++h) acc[h] = s_qb[h];
    const float* krow = k + (size_t)j * INNER;
#pragma unroll
    for (int h = 0; h < NH; ++h) {
      float s = 0.f;
#pragma unroll
      for (int dd = 0; dd < 8; ++dd) {
        const float4 k4 = *(const float4*)(krow + h * HD + dd * 4);
        const float4 q4 = *(const float4*)&s_q[h * HD + dd * 4];
        s += k4.x * q4.x + k4.y * q4.y + k4.z * q4.z + k4.w * q4.w;
      }
      acc[h] += s;
    }
    const float4* erow = (const float4*)(edges + ((size_t)i * N_NODES + j) * EDGE_DIM);
#pragma unroll
    for (int cc = 0; cc < 16; ++cc) {
      const float4 ev = erow[cc];
#pragma unroll
      for (int h = 0; h < NH; ++h) {
        const float4 qe4 = *(const float4*)&s_qe[h * EDGE_DIM + cc * 4];
        acc[h] += ev.x * qe4.x + ev.y * qe4.y + ev.z * qe4.z + ev.w * qe4.w;
      }
    }
#pragma unroll
    for (int h = 0; h < NH; ++h) s_attn[h][j] = acc[h] * scale;
  }
  __syncthreads();

  // ---- head-0 row mean (reference quirk: broadcast to all heads) ----
  {
    float m = s_attn[0][tid] + s_attn[0][tid + 256];
#pragma unroll
    for (int off = 32; off > 0; off >>= 1) m += __shfl_xor(m, off, 64);
    if (lane == 0) s_red[wid] = m;
  }
  __syncthreads();
  if (tid == 0) s_mean = (s_red[0] + s_red[1] + s_red[2] + s_red[3]) * (1.f / 512.f);
  __syncthreads();

  // ---- exp(x-mean)*adj, per-head row sums ----
  float hsum[NH] = {0.f, 0.f, 0.f, 0.f, 0.f, 0.f, 0.f, 0.f};
  const float mean = s_mean;
  for (int p = 0; p < 2; ++p) {
    const int j = tid + p * 256;
    const float aj = s_adj[j];
#pragma unroll
    for (int h = 0; h < NH; ++h) {
      const float e = __expf(s_attn[h][j] - mean) * aj;
      s_attn[h][j] = e;
      hsum[h] += e;
    }
  }
#pragma unroll
  for (int h = 0; h < NH; ++h) {
    float m = hsum[h];
#pragma unroll
    for (int off = 32; off > 0; off >>= 1) m += __shfl_xor(m, off, 64);
    if (lane == 0) s_red[wid * NH + h] = m;
  }
  __syncthreads();
  if (tid < NH) {
    const float dsum = s_red[tid] + s_red[NH + tid] + s_red[2 * NH + tid] + s_red[3 * NH + tid];
    s_rdenom[tid] = (dsum == 0.f) ? 1.f : (1.f / dsum);
    s_asum[tid]   = (dsum == 0.f) ? 0.f : 1.f;
  }
  __syncthreads();

  // ---- pass 2: ae[h][c] = sum_j attn*edges ;  accV = sum_j attn*v ----
  const int c  = tid & 63;
  const int hp = tid >> 6;   // ae heads hp and hp+4 (uniform per wave)
  const int hC = tid >> 5;   // av head (2 per wave)
  float accA = 0.f, accB = 0.f, accV = 0.f;
  const float* ecol = edges + (size_t)i * N_NODES * EDGE_DIM + c;
  const float* vcol = v + hC * HD + (tid & 31);
  const float4* attnA = (const float4*)(&s_attn[hp][0]);
  const float4* attnB = (const float4*)(&s_attn[hp + 4][0]);
  const float4* attnC = (const float4*)(&s_attn[hC][0]);
#pragma unroll 2
  for (int j4 = 0; j4 < N_NODES / 4; ++j4) {
    const float4 aA = attnA[j4];
    const float4 aB = attnB[j4];
    const float4 aC = attnC[j4];
    const int j = j4 * 4;
    const float e0 = ecol[(size_t)(j + 0) * EDGE_DIM];
    const float e1 = ecol[(size_t)(j + 1) * EDGE_DIM];
    const float e2 = ecol[(size_t)(j + 2) * EDGE_DIM];
    const float e3 = ecol[(size_t)(j + 3) * EDGE_DIM];
    const float v0 = vcol[(j + 0) * INNER];
    const float v1 = vcol[(j + 1) * INNER];
    const float v2 = vcol[(j + 2) * INNER];
    const float v3 = vcol[(j + 3) * INNER];
    accA = fmaf(aA.x, e0, accA); accA = fmaf(aA.y, e1, accA);
    accA = fmaf(aA.z, e2, accA); accA = fmaf(aA.w, e3, accA);
    accB = fmaf(aB.x, e0, accB); accB = fmaf(aB.y, e1, accB);
    accB = fmaf(aB.z, e2, accB); accB = fmaf(aB.w, e3, accB);
    accV = fmaf(aC.x, v0, accV); accV = fmaf(aC.y, v1, accV);
    accV = fmaf(aC.z, v2, accV); accV = fmaf(aC.w, v3, accV);
  }
  accA *= s_rdenom[hp];
  accB *= s_rdenom[hp + 4];
  accV *= s_rdenom[hC];
  s_ae[hp * EDGE_DIM + c]       = accA;
  s_ae[(hp + 4) * EDGE_DIM + c] = accB;
  __syncthreads();

  // ---- epilogue: out[n] = accV + ae[h,:] @ We[:,n] + asum[h]*be[n] ----
  {
    const int n = tid;
    const int h = hC;
    float o = accV + s_asum[h] * be[n];
    const float* aeh  = &s_ae[h * EDGE_DIM];
    const float* wcol = We + n;
#pragma unroll 8
    for (int cc = 0; cc < EDGE_DIM; ++cc)
      o = fmaf(aeh[cc], wcol[(size_t)cc * INNER], o);
    out[(size_t)i * INNER + n] = o;
  }
}

extern "C" void kernel_launch(void* const* d_in, const int* in_sizes, int n_in,
                              void* d_out, int out_size, void* d_ws, size_t ws_size,
                              hipStream_t stream) {
  const float* nodes     = (const float*)d_in[0];
  const float* edges     = (const float*)d_in[1];
  const int*   adjacency = (const int*)d_in[2];
  const float* Wq = (const float*)d_in[3];
  const float* bq = (const float*)d_in[4];
  const float* Wk = (const float*)d_in[5];
  const float* bk = (const float*)d_in[6];
  const float* Wv = (const float*)d_in[7];
  const float* bv = (const float*)d_in[8];
  const float* We = (const float*)d_in[9];
  const float* be = (const float*)d_in[10];

  float* q = (float*)d_ws;
  float* k = q + (size_t)N_NODES * INNER;
  float* v = k + (size_t)N_NODES * INNER;

  proj_qkv<<<dim3(N_NODES / 4), dim3(256), 0, stream>>>(
      nodes, Wq, bq, Wk, bk, Wv, bv, q, k, v);
  fused_graph_attn<<<dim3(N_NODES), dim3(256), 0, stream>>>(
      edges, adjacency, q, k, v, We, be, (float*)d_out);
}

// Round 4
// 208.432 us; speedup vs baseline: 1.0712x; 1.0712x over previous
//
#include <hip/hip_runtime.h>

#define N_NODES 512
#define INNER   256
#define IN_DIM  128
#define EDGE_DIM 64
#define NH 8
#define HD 32

// ---------------------------------------------------------------------------
// Kernel 1: q/k/v projections. Grid 3*512: block (m, i) computes row i of
// matrix m. Thread n owns output column n. nodes row reads are uniform ->
// scalar loads; W reads coalesced. 6 blocks/CU.
// ---------------------------------------------------------------------------
__global__ __launch_bounds__(256) void proj_qkv(
    const float* __restrict__ nodes,
    const float* __restrict__ Wq, const float* __restrict__ bq,
    const float* __restrict__ Wk, const float* __restrict__ bk,
    const float* __restrict__ Wv, const float* __restrict__ bv,
    float* __restrict__ q, float* __restrict__ k, float* __restrict__ v) {
  const int m = blockIdx.x >> 9;
  const int i = blockIdx.x & 511;
  const int n = threadIdx.x;
  const float* __restrict__ W = (m == 0) ? Wq : (m == 1) ? Wk : Wv;
  const float* __restrict__ b = (m == 0) ? bq : (m == 1) ? bk : bv;
  float*       __restrict__ o = (m == 0) ? q  : (m == 1) ? k  : v;
  const float* nrow = nodes + (size_t)i * IN_DIM;
  float a = 0.f;
#pragma unroll 4
  for (int c = 0; c < IN_DIM; ++c)
    a = fmaf(nrow[c], W[(size_t)c * INNER + n], a);
  o[(size_t)i * INNER + n] = a + b[n];
}

// ---------------------------------------------------------------------------
// Kernel 2: fused attention. One 1024-thread block per query row i (16 waves,
// 4/SIMD via launch_bounds). Edge projection eliminated algebraically:
//   sim[h,j] = q_i.k_j + edges[i,j,:].qe[h] + qb[h]
//   out[n]   = sum_j attn v[j,n] + ae[h,:]@We[:,n] + asum[h]*be[n]
// Pass 1: thread (j, head-group of 4). Pass 2: j split 2-way (ae) / 4-way
// (accV) with LDS partial reduction.
// ---------------------------------------------------------------------------
__global__ __launch_bounds__(1024, 4) void fused_graph_attn(
    const float* __restrict__ edges, const int* __restrict__ adjacency,
    const float* __restrict__ q, const float* __restrict__ k,
    const float* __restrict__ v,
    const float* __restrict__ We, const float* __restrict__ be,
    float* __restrict__ out) {
  const int i    = blockIdx.x;
  const int tid  = threadIdx.x;
  const int wid  = tid >> 6;
  const int lane = tid & 63;

  __shared__ float s_q[INNER];
  __shared__ float s_qe[NH * EDGE_DIM];
  __shared__ float s_qb[NH];
  __shared__ float s_adj[N_NODES];
  __shared__ float s_attn[NH][N_NODES];
  __shared__ float s_red[64];
  __shared__ float s_mean;
  __shared__ float s_rdenom[NH];
  __shared__ float s_asum[NH];
  __shared__ float s_aep[2][NH * EDGE_DIM];
  __shared__ float s_ae[NH * EDGE_DIM];
  __shared__ float s_vp[4][INNER];

  // ---- stage q row + adjacency row ----
  if (tid < 256) s_q[tid] = q[(size_t)i * INNER + tid];
  if (tid >= 256 && tid < 768)
    s_adj[tid - 256] = (float)adjacency[(size_t)i * N_NODES + (tid - 256)];
  __syncthreads();

  // ---- qe[h][c] = q_h . We[c, h*32..] ; qb[h] = q_h . be_h ----
  if (tid < 512) {
    const int h = tid >> 6, c = tid & 63;
    const float* wrow = We + (size_t)c * INNER + h * HD;
    const float* qh   = &s_q[h * HD];
    float acc = 0.f;
#pragma unroll
    for (int dd = 0; dd < 8; ++dd) {
      const float4 w4 = *(const float4*)(wrow + dd * 4);
      const float4 q4 = *(const float4*)(qh + dd * 4);
      acc += q4.x * w4.x + q4.y * w4.y + q4.z * w4.z + q4.w * w4.w;
    }
    s_qe[tid] = acc;
  } else if (tid < 520) {
    const int h = tid - 512;
    float acc = 0.f;
    for (int d = 0; d < HD; ++d) acc += s_q[h * HD + d] * be[h * HD + d];
    s_qb[h] = acc;
  }
  __syncthreads();

  // ---- pass 1: sim for 4 heads per thread ----
  const int j  = tid & 511;
  const int hg = tid >> 9;        // head group: heads hg*4 .. hg*4+3
  const int h0 = hg * 4;
  const float scale = 0.17677669529663687f;  // 1/sqrt(32)
  float simv[4];
  {
    float acc[4];
#pragma unroll
    for (int h = 0; h < 4; ++h) acc[h] = s_qb[h0 + h];
    const float* krow = k + (size_t)j * INNER + h0 * HD;
#pragma unroll
    for (int h = 0; h < 4; ++h) {
      float s = 0.f;
#pragma unroll 2
      for (int dd = 0; dd < 8; ++dd) {
        const float4 k4 = *(const float4*)(krow + h * HD + dd * 4);
        const float4 q4 = *(const float4*)&s_q[(h0 + h) * HD + dd * 4];
        s += k4.x * q4.x + k4.y * q4.y + k4.z * q4.z + k4.w * q4.w;
      }
      acc[h] += s;
    }
    const float4* erow = (const float4*)(edges + ((size_t)i * N_NODES + j) * EDGE_DIM);
#pragma unroll 4
    for (int cc = 0; cc < 16; ++cc) {
      const float4 ev = erow[cc];
#pragma unroll
      for (int h = 0; h < 4; ++h) {
        const float4 qe4 = *(const float4*)&s_qe[(h0 + h) * EDGE_DIM + cc * 4];
        acc[h] += ev.x * qe4.x + ev.y * qe4.y + ev.z * qe4.z + ev.w * qe4.w;
      }
    }
#pragma unroll
    for (int h = 0; h < 4; ++h) {
      simv[h] = acc[h] * scale;
      s_attn[h0 + h][j] = simv[h];
    }
  }
  __syncthreads();

  // ---- head-0 row mean (reference quirk: broadcast to all heads) ----
  {
    float m = (tid < 512) ? s_attn[0][tid] : 0.f;
#pragma unroll
    for (int off = 32; off > 0; off >>= 1) m += __shfl_xor(m, off, 64);
    if (lane == 0) s_red[wid] = m;
  }
  __syncthreads();
  if (tid == 0) {
    float m = 0.f;
#pragma unroll
    for (int w = 0; w < 16; ++w) m += s_red[w];
    s_mean = m * (1.f / 512.f);
  }
  __syncthreads();

  // ---- exp(sim-mean)*adj for this thread's 4 heads; per-head row sums ----
  {
    const float mean = s_mean;
    const float aj   = s_adj[j];
    float hs[4];
#pragma unroll
    for (int h = 0; h < 4; ++h) {
      const float e = __expf(simv[h] - mean) * aj;
      s_attn[h0 + h][j] = e;
      hs[h] = e;
    }
#pragma unroll
    for (int h = 0; h < 4; ++h) {
      float m = hs[h];
#pragma unroll
      for (int off = 32; off > 0; off >>= 1) m += __shfl_xor(m, off, 64);
      if (lane == 0) s_red[wid * 4 + h] = m;
    }
  }
  __syncthreads();
  if (tid < NH) {
    const int hg2 = tid >> 2, hh = tid & 3;
    float dsum = 0.f;
#pragma unroll
    for (int w = 0; w < 8; ++w) dsum += s_red[(hg2 * 8 + w) * 4 + hh];
    s_rdenom[tid] = (dsum == 0.f) ? 1.f : (1.f / dsum);
    s_asum[tid]   = (dsum == 0.f) ? 0.f : 1.f;
  }
  __syncthreads();

  // ---- pass 2a: ae partials. thread = (c, head, j-half), 256 j each ----
  {
    const int c  = tid & 63;
    const int ha = (tid >> 6) & 7;
    const int jh = tid >> 9;
    const float* att  = &s_attn[ha][jh * 256];
    const float* ecol = edges + ((size_t)i * N_NODES + jh * 256) * EDGE_DIM + c;
    float acc = 0.f;
#pragma unroll 4
    for (int jj = 0; jj < 256; ++jj)
      acc = fmaf(att[jj], ecol[(size_t)jj * EDGE_DIM], acc);
    s_aep[jh][ha * EDGE_DIM + c] = acc;
  }
  // ---- pass 2b: accV partials. thread = (n, j-quarter), 128 j each ----
  {
    const int n  = tid & 255;
    const int jq = tid >> 8;
    const int hv = n >> 5;
    const float* att  = &s_attn[hv][jq * 128];
    const float* vcol = v + (size_t)(jq * 128) * INNER + n;
    float acc = 0.f;
#pragma unroll 4
    for (int jj = 0; jj < 128; ++jj)
      acc = fmaf(att[jj], vcol[(size_t)jj * INNER], acc);
    s_vp[jq][n] = acc;
  }
  __syncthreads();

  // ---- combine ae partials, normalize ----
  if (tid < 512) {
    const int ha = tid >> 6;
    s_ae[tid] = (s_aep[0][tid] + s_aep[1][tid]) * s_rdenom[ha];
  }
  __syncthreads();

  // ---- epilogue: out[n] = accV + ae[h,:] @ We[:,n] + asum[h]*be[n] ----
  if (tid < 256) {
    const int n = tid;
    const int h = n >> 5;
    float o = (s_vp[0][n] + s_vp[1][n] + s_vp[2][n] + s_vp[3][n]) * s_rdenom[h]
              + s_asum[h] * be[n];
    const float* aeh  = &s_ae[h * EDGE_DIM];
    const float* wcol = We + n;
#pragma unroll 8
    for (int cc = 0; cc < EDGE_DIM; ++cc)
      o = fmaf(aeh[cc], wcol[(size_t)cc * INNER], o);
    out[(size_t)i * INNER + n] = o;
  }
}

extern "C" void kernel_launch(void* const* d_in, const int* in_sizes, int n_in,
                              void* d_out, int out_size, void* d_ws, size_t ws_size,
                              hipStream_t stream) {
  const float* nodes     = (const float*)d_in[0];
  const float* edges     = (const float*)d_in[1];
  const int*   adjacency = (const int*)d_in[2];
  const float* Wq = (const float*)d_in[3];
  const float* bq = (const float*)d_in[4];
  const float* Wk = (const float*)d_in[5];
  const float* bk = (const float*)d_in[6];
  const float* Wv = (const float*)d_in[7];
  const float* bv = (const float*)d_in[8];
  const float* We = (const float*)d_in[9];
  const float* be = (const float*)d_in[10];

  float* q = (float*)d_ws;
  float* k = q + (size_t)N_NODES * INNER;
  float* v = k + (size_t)N_NODES * INNER;

  proj_qkv<<<dim3(3 * N_NODES), dim3(256), 0, stream>>>(
      nodes, Wq, bq, Wk, bk, Wv, bv, q, k, v);
  fused_graph_attn<<<dim3(N_NODES), dim3(1024), 0, stream>>>(
      edges, adjacency, q, k, v, We, be, (float*)d_out);
}